// Round 1
// baseline (1231.290 us; speedup 1.0000x reference)
//
#include <hip/hip_runtime.h>
#include <math.h>

#define B_N  4
#define CIN  64
#define COUT 64
#define H_N  128
#define W_N  128

// Transpose weight (3, Cout, Cin, 3, 3) -> wt[h][t][c][o]  (t = ky*3+kx)
// so the hot-loop weight read is o-contiguous (coalesced across the 64 o-lanes).
__global__ void wt_transpose(const float* __restrict__ w, float* __restrict__ wt) {
    int idx = blockIdx.x * blockDim.x + threadIdx.x;
    if (idx >= 3 * 9 * CIN * COUT) return;
    int o  = idx & 63;
    int c  = (idx >> 6) & 63;
    int hk = idx >> 12;          // h*9 + t
    int t  = hk % 9;
    int h  = hk / 9;
    wt[idx] = w[(((size_t)(h * COUT) + o) * CIN + c) * 9 + t];
}

// Block: 256 threads = 64 o-lanes x 4 pixel-groups; each thread: one o, 8
// consecutive x, full (tap, c) reduction. h-selection is exact (fp64) and
// wave-uniform (all o-lanes share the pixel set) -> uniform branches.
template <bool TR>
__global__ __launch_bounds__(256)
void conv25d(const float* __restrict__ inp, const float* __restrict__ depth,
             const float* __restrict__ wsrc, const float* __restrict__ bias,
             const int* __restrict__ fptr, float* __restrict__ out) {
    int bid = blockIdx.x;
    int xt  = bid & 3;           // W/32 tiles
    int y   = (bid >> 2) & (H_N - 1);
    int b   = bid >> 9;          // B index
    int o   = threadIdx.x & 63;
    int q   = threadIdx.x >> 6;  // 0..3
    int x0  = xt * 32 + q * 8;

    double fd = (double)(*fptr);

    float acc[8];
    float bv = bias[o];
#pragma unroll
    for (int i = 0; i < 8; ++i) acc[i] = bv;

    const float* dcen = depth + ((size_t)b * H_N + y) * W_N;
    float d0[8];
#pragma unroll
    for (int i = 0; i < 8; ++i) d0[i] = dcen[x0 + i];

    for (int t = 0; t < 9; ++t) {
        int dy = t / 3 - 1, dx = t % 3 - 1;
        int yy = y + dy;
        if (yy < 0 || yy >= H_N) continue;  // padded row: input=0 -> no contribution

        const float* drow = depth + ((size_t)b * H_N + yy) * W_N;
        int hsel[8];
#pragma unroll
        for (int i = 0; i < 8; ++i) {
            int xx = x0 + i + dx;
            int h = -1;
            if (xx >= 0 && xx < W_N) {
                double dd = (double)d0[i];
                double s0 = dd / fd;
                if (s0 > 0.0) {
                    // exact: intervals [d0+(h-1)s0 - s0/2, d0+(h-1)s0 + s0/2)
                    double u = ((double)drow[xx] - dd) / s0 + 1.5;
                    double uf = floor(u);
                    if (uf >= 0.0 && uf <= 2.0) h = (int)uf;
                }
            }
            hsel[i] = h;
        }

        const float* irow = inp + ((size_t)b * CIN * H_N + yy) * W_N;
        for (int c = 0; c < CIN; ++c) {
            float w0, w1, w2;
            if (TR) {
                const float* wb = wsrc + ((size_t)t * CIN + c) * COUT + o;
                w0 = wb[0 * 9 * CIN * COUT];
                w1 = wb[1 * 9 * CIN * COUT];
                w2 = wb[2 * 9 * CIN * COUT];
            } else {
                const float* wb = wsrc + ((size_t)o * CIN + c) * 9 + t;
                w0 = wb[0 * (size_t)COUT * CIN * 9];
                w1 = wb[1 * (size_t)COUT * CIN * 9];
                w2 = wb[2 * (size_t)COUT * CIN * 9];
            }
            const float* ir = irow + (size_t)c * H_N * W_N;
#pragma unroll
            for (int i = 0; i < 8; ++i) {
                int h = hsel[i];
                if (h >= 0) {
                    float xv = ir[x0 + i + dx];
                    float wv = (h == 0) ? w0 : ((h == 1) ? w1 : w2);
                    acc[i] = fmaf(xv, wv, acc[i]);
                }
            }
        }
    }

    float* orow = out + (((size_t)b * COUT + o) * H_N + y) * W_N;
#pragma unroll
    for (int i = 0; i < 8; ++i) orow[x0 + i] = acc[i];
}

extern "C" void kernel_launch(void* const* d_in, const int* in_sizes, int n_in,
                              void* d_out, int out_size, void* d_ws, size_t ws_size,
                              hipStream_t stream) {
    const float* inp   = (const float*)d_in[0];
    const float* depth = (const float*)d_in[1];
    const float* w     = (const float*)d_in[2];
    const float* bias  = (const float*)d_in[3];
    const int*   f     = (const int*)d_in[4];
    float* out = (float*)d_out;

    const size_t WT_BYTES = (size_t)3 * 9 * CIN * COUT * sizeof(float);
    dim3 grid(B_N * H_N * (W_N / 32));   // 2048 blocks

    if (ws_size >= WT_BYTES) {
        float* wt = (float*)d_ws;
        wt_transpose<<<(3 * 9 * CIN * COUT + 255) / 256, 256, 0, stream>>>(w, wt);
        conv25d<true><<<grid, 256, 0, stream>>>(inp, depth, wt, bias, f, out);
    } else {
        conv25d<false><<<grid, 256, 0, stream>>>(inp, depth, w, bias, f, out);
    }
}

// Round 2
// 106.373 us; speedup vs baseline: 11.5752x; 11.5752x over previous
//
#include <hip/hip_runtime.h>
#include <math.h>

#define B_N  4
#define CIN  64
#define COUT 64
#define H_N  128
#define W_N  128

typedef _Float16 half8 __attribute__((ext_vector_type(8)));
typedef float    f32x4 __attribute__((ext_vector_type(4)));

#define KTOT   1728              // 27 groups (t*3+h) * 64 c
#define NSTEP  54                // KTOT / 32
#define WA_BYTES ((size_t)NSTEP * 4 * 64 * 8 * 2)   // 221184 B

// ---- pack weights (3,Cout,Cin,3,3) fp32 -> f16 in MFMA A-fragment order ----
// A-fragment for K-step s, m-tile mt, lane l: 8 f16 = A[m=mt*16+(l&15)][k=s*32+(l>>4)*8+j]
// k -> (t,h,c): g=k>>6, c=k&63, t=g/3, h=g%3
__global__ void wprep(const float* __restrict__ w, _Float16* __restrict__ wa) {
    int idx = blockIdx.x * 256 + threadIdx.x;        // (s, mt, lane)
    if (idx >= NSTEP * 4 * 64) return;
    int lane = idx & 63;
    int mt   = (idx >> 6) & 3;
    int s    = idx >> 8;
    int m    = mt * 16 + (lane & 15);
    int kl0  = (lane >> 4) * 8;
    _Float16 v[8];
#pragma unroll
    for (int j = 0; j < 8; ++j) {
        int k = s * 32 + kl0 + j;
        int g = k >> 6;
        int c = k & 63;
        int t = g / 3;
        int h = g % 3;
        v[j] = (_Float16)w[(((size_t)(h * COUT) + m) * CIN + c) * 9 + t];
    }
    *(int4*)&wa[(size_t)idx * 8] = *(int4*)v;
}

#define XS_STRIDE 72             // 64 c + 8 pad (breaks 128B bank cycle)
#define XS_ROW    (130 * XS_STRIDE)

// Block = one (b,y): 128 pixels x 64 Cout. 4 waves x 32 pixels.
__global__ __launch_bounds__(256)
void conv_mfma(const float* __restrict__ inp, const float* __restrict__ depth,
               const _Float16* __restrict__ wa, const float* __restrict__ bias,
               const int* __restrict__ fptr, float* __restrict__ out) {
    __shared__ _Float16 Xs[3 * XS_ROW];              // 56160 B

    int bid  = blockIdx.x;
    int y    = bid & (H_N - 1);
    int b    = bid >> 7;
    int tid  = threadIdx.x;
    int lane = tid & 63;
    int wid  = tid >> 6;
    int p0   = wid * 32;
    int ln15 = lane & 15;
    int quad = lane >> 4;

    // ---- stage 3 input rows (dy=-1,0,1), transposed to [x][c], f16 ----
    {
        int x     = tid & 127;
        int chalf = tid >> 7;                        // c in [chalf*32, chalf*32+32)
        for (int dyi = 0; dyi < 3; ++dyi) {
            int yy = y + dyi - 1;
            _Float16 buf[32];
            if (yy >= 0 && yy < H_N) {
                const float* src = inp + (((size_t)b * CIN + chalf * 32) * H_N + yy) * W_N + x;
#pragma unroll
                for (int cc = 0; cc < 32; ++cc)
                    buf[cc] = (_Float16)src[(size_t)cc * H_N * W_N];
            } else {
#pragma unroll
                for (int cc = 0; cc < 32; ++cc) buf[cc] = (_Float16)0.f;
            }
            _Float16* dst = &Xs[dyi * XS_ROW + (x + 1) * XS_STRIDE + chalf * 32];
#pragma unroll
            for (int k = 0; k < 4; ++k)
                *(int4*)&dst[k * 8] = *(int4*)&buf[k * 8];
        }
        // zero pads at x=-1 (row 0) and x=128 (row 129)
        if (tid < 48) {
            int dyi = tid / 16;
            int rem = tid % 16;
            int xi  = (rem >= 8) ? 129 : 0;
            int k8  = rem & 7;
            int4 z  = {0, 0, 0, 0};
            *(int4*)&Xs[dyi * XS_ROW + xi * XS_STRIDE + k8 * 8] = z;
        }
    }

    // ---- per-lane h-selection packs (exact fp64, identical to R1 formula) ----
    double fd = (double)(*fptr);
    unsigned hpk[2];
#pragma unroll
    for (int nt = 0; nt < 2; ++nt) {
        int x = p0 + nt * 16 + ln15;
        float d0f = depth[((size_t)b * H_N + y) * W_N + x];
        double dd = (double)d0f;
        double s0 = dd / fd;
        unsigned pk = 0;
        for (int t = 0; t < 9; ++t) {
            int dy = t / 3 - 1, dx = t % 3 - 1;
            int yy = y + dy, xx = x + dx;
            float dwf = (yy >= 0 && yy < H_N && xx >= 0 && xx < W_N)
                        ? depth[((size_t)b * H_N + yy) * W_N + xx] : 0.f;
            int h = -1;
            if (s0 > 0.0) {
                double u  = ((double)dwf - dd) / s0 + 1.5;
                double uf = floor(u);
                if (uf >= 0.0 && uf <= 2.0) h = (int)uf;
            }
            pk |= (unsigned)(h + 1) << (2 * t);
        }
        hpk[nt] = pk;
    }

    __syncthreads();

    // ---- MFMA main loop: 27 (t,h) groups x 2 K-steps ----
    f32x4 acc[4][2];
#pragma unroll
    for (int mt = 0; mt < 4; ++mt)
#pragma unroll
        for (int nt = 0; nt < 2; ++nt) acc[mt][nt] = (f32x4){0.f, 0.f, 0.f, 0.f};

    for (int t = 0; t < 9; ++t) {
        int dyi = t / 3;
        int dx  = t % 3 - 1;
        int boff0 = dyi * XS_ROW + (p0 + 0  + ln15 + dx + 1) * XS_STRIDE + quad * 8;
        int boff1 = dyi * XS_ROW + (p0 + 16 + ln15 + dx + 1) * XS_STRIDE + quad * 8;
        int hb0 = (hpk[0] >> (2 * t)) & 3;
        int hb1 = (hpk[1] >> (2 * t)) & 3;
#pragma unroll
        for (int h = 0; h < 3; ++h) {
            bool m0 = (hb0 == h + 1);
            bool m1 = (hb1 == h + 1);
            int sbase = (t * 3 + h) * 2;
#pragma unroll
            for (int kk = 0; kk < 2; ++kk) {
                int s = sbase + kk;
                half8 a[4];
#pragma unroll
                for (int mt = 0; mt < 4; ++mt)
                    a[mt] = *(const half8*)&wa[(((size_t)s * 4 + mt) * 64 + lane) * 8];
                half8 b0 = *(const half8*)&Xs[boff0 + kk * 32];
                half8 b1 = *(const half8*)&Xs[boff1 + kk * 32];
                half8 z  = {(_Float16)0.f, (_Float16)0.f, (_Float16)0.f, (_Float16)0.f,
                            (_Float16)0.f, (_Float16)0.f, (_Float16)0.f, (_Float16)0.f};
                b0 = m0 ? b0 : z;
                b1 = m1 ? b1 : z;
#pragma unroll
                for (int mt = 0; mt < 4; ++mt) {
                    acc[mt][0] = __builtin_amdgcn_mfma_f32_16x16x32_f16(a[mt], b0, acc[mt][0], 0, 0, 0);
                    acc[mt][1] = __builtin_amdgcn_mfma_f32_16x16x32_f16(a[mt], b1, acc[mt][1], 0, 0, 0);
                }
            }
        }
    }

    // ---- epilogue: D[m=o: quad*4+r][n=pixel: lane&15] + bias ----
#pragma unroll
    for (int mt = 0; mt < 4; ++mt) {
#pragma unroll
        for (int nt = 0; nt < 2; ++nt) {
            int x = p0 + nt * 16 + ln15;
#pragma unroll
            for (int r = 0; r < 4; ++r) {
                int o = mt * 16 + quad * 4 + r;
                out[(((size_t)b * COUT + o) * H_N + y) * W_N + x] = acc[mt][nt][r] + bias[o];
            }
        }
    }
}

// ---- fallback scalar kernel (R1, used only if ws too small) ----
__global__ __launch_bounds__(256)
void conv25d(const float* __restrict__ inp, const float* __restrict__ depth,
             const float* __restrict__ wsrc, const float* __restrict__ bias,
             const int* __restrict__ fptr, float* __restrict__ out) {
    int bid = blockIdx.x;
    int xt  = bid & 3;
    int y   = (bid >> 2) & (H_N - 1);
    int b   = bid >> 9;
    int o   = threadIdx.x & 63;
    int q   = threadIdx.x >> 6;
    int x0  = xt * 32 + q * 8;
    double fd = (double)(*fptr);
    float acc[8];
    float bv = bias[o];
#pragma unroll
    for (int i = 0; i < 8; ++i) acc[i] = bv;
    const float* dcen = depth + ((size_t)b * H_N + y) * W_N;
    float d0[8];
#pragma unroll
    for (int i = 0; i < 8; ++i) d0[i] = dcen[x0 + i];
    for (int t = 0; t < 9; ++t) {
        int dy = t / 3 - 1, dx = t % 3 - 1;
        int yy = y + dy;
        if (yy < 0 || yy >= H_N) continue;
        const float* drow = depth + ((size_t)b * H_N + yy) * W_N;
        int hsel[8];
#pragma unroll
        for (int i = 0; i < 8; ++i) {
            int xx = x0 + i + dx;
            int h = -1;
            if (xx >= 0 && xx < W_N) {
                double dd = (double)d0[i];
                double s0 = dd / fd;
                if (s0 > 0.0) {
                    double u = ((double)drow[xx] - dd) / s0 + 1.5;
                    double uf = floor(u);
                    if (uf >= 0.0 && uf <= 2.0) h = (int)uf;
                }
            }
            hsel[i] = h;
        }
        const float* irow = inp + ((size_t)b * CIN * H_N + yy) * W_N;
        for (int c = 0; c < CIN; ++c) {
            const float* wb = wsrc + ((size_t)o * CIN + c) * 9 + t;
            float w0 = wb[0], w1 = wb[(size_t)COUT * CIN * 9], w2 = wb[2 * (size_t)COUT * CIN * 9];
            const float* ir = irow + (size_t)c * H_N * W_N;
#pragma unroll
            for (int i = 0; i < 8; ++i) {
                int h = hsel[i];
                if (h >= 0) {
                    float wv = (h == 0) ? w0 : ((h == 1) ? w1 : w2);
                    acc[i] = fmaf(ir[x0 + i + dx], wv, acc[i]);
                }
            }
        }
    }
    float* orow = out + (((size_t)b * COUT + o) * H_N + y) * W_N;
#pragma unroll
    for (int i = 0; i < 8; ++i) orow[x0 + i] = acc[i];
}

extern "C" void kernel_launch(void* const* d_in, const int* in_sizes, int n_in,
                              void* d_out, int out_size, void* d_ws, size_t ws_size,
                              hipStream_t stream) {
    const float* inp   = (const float*)d_in[0];
    const float* depth = (const float*)d_in[1];
    const float* w     = (const float*)d_in[2];
    const float* bias  = (const float*)d_in[3];
    const int*   f     = (const int*)d_in[4];
    float* out = (float*)d_out;

    if (ws_size >= WA_BYTES) {
        _Float16* wa = (_Float16*)d_ws;
        wprep<<<NSTEP, 256, 0, stream>>>(w, wa);
        conv_mfma<<<B_N * H_N, 256, 0, stream>>>(inp, depth, wa, bias, f, out);
    } else {
        conv25d<<<B_N * H_N * (W_N / 32), 256, 0, stream>>>(inp, depth, w, bias, f, out);
    }
}

// Round 4
// 105.453 us; speedup vs baseline: 11.6762x; 1.0087x over previous
//
#include <hip/hip_runtime.h>
#include <math.h>

#define B_N  4
#define CIN  64
#define COUT 64
#define H_N  128
#define W_N  128

typedef _Float16 half8 __attribute__((ext_vector_type(8)));
typedef float    f32x4 __attribute__((ext_vector_type(4)));

#define KTOT   1728              // 27 groups (t*3+h) * 64 c
#define NSTEP  54                // KTOT / 32
#define WA_BYTES ((size_t)NSTEP * 4 * 64 * 8 * 2)   // 221184 B

// ---- pack weights (3,Cout,Cin,3,3) fp32 -> f16 in MFMA A-fragment order ----
// A-fragment for K-step s, m-tile mt, lane l: 8 f16 = A[m=mt*16+(l&15)][k=s*32+(l>>4)*8+j]
// k -> (t,h,c): g=k>>6, c=k&63, t=g/3, h=g%3
__global__ void wprep(const float* __restrict__ w, _Float16* __restrict__ wa) {
    int idx = blockIdx.x * 256 + threadIdx.x;        // (s, mt, lane)
    if (idx >= NSTEP * 4 * 64) return;
    int lane = idx & 63;
    int mt   = (idx >> 6) & 3;
    int s    = idx >> 8;
    int m    = mt * 16 + (lane & 15);
    int kl0  = (lane >> 4) * 8;
    _Float16 v[8];
#pragma unroll
    for (int j = 0; j < 8; ++j) {
        int k = s * 32 + kl0 + j;
        int g = k >> 6;
        int c = k & 63;
        int t = g / 3;
        int h = g % 3;
        v[j] = (_Float16)w[(((size_t)(h * COUT) + m) * CIN + c) * 9 + t];
    }
    *(int4*)&wa[(size_t)idx * 8] = *(int4*)v;
}

#define XS_STRIDE 72             // 64 c + 8 pad (b128 reads at min 2-way aliasing = free)
#define XS_ROW    (130 * XS_STRIDE)

// Block = one (b,y): 128 pixels x 64 Cout. 4 waves x 32 pixels.
// R3 change: per-tap __syncthreads() locksteps the waves so the block's A-tile
// reads hit L1 (R2 let waves drift -> every wave streamed 221KB from L2, ~7x
// over per-CU L2 BW). A-fragments for a whole tap (24 x 16B) are batch-loaded
// into registers -> one L2 latency per tap, max MLP.
__global__ __launch_bounds__(256)
void conv_mfma(const float* __restrict__ inp, const float* __restrict__ depth,
               const _Float16* __restrict__ wa, const float* __restrict__ bias,
               const int* __restrict__ fptr, float* __restrict__ out) {
    __shared__ _Float16 Xs[3 * XS_ROW];              // 56160 B

    int bid  = blockIdx.x;
    int y    = bid & (H_N - 1);
    int b    = bid >> 7;
    int tid  = threadIdx.x;
    int lane = tid & 63;
    int wid  = tid >> 6;
    int p0   = wid * 32;
    int ln15 = lane & 15;
    int quad = lane >> 4;

    // ---- stage 3 input rows (dy=-1,0,1), transposed to [x][c], f16 ----
    {
        int x     = tid & 127;
        int chalf = tid >> 7;                        // c in [chalf*32, chalf*32+32)
        for (int dyi = 0; dyi < 3; ++dyi) {
            int yy = y + dyi - 1;
            _Float16 buf[32];
            if (yy >= 0 && yy < H_N) {
                const float* src = inp + (((size_t)b * CIN + chalf * 32) * H_N + yy) * W_N + x;
#pragma unroll
                for (int cc = 0; cc < 32; ++cc)
                    buf[cc] = (_Float16)src[(size_t)cc * H_N * W_N];
            } else {
#pragma unroll
                for (int cc = 0; cc < 32; ++cc) buf[cc] = (_Float16)0.f;
            }
            _Float16* dst = &Xs[dyi * XS_ROW + (x + 1) * XS_STRIDE + chalf * 32];
#pragma unroll
            for (int k = 0; k < 4; ++k)
                *(int4*)&dst[k * 8] = *(int4*)&buf[k * 8];
        }
        // zero pads at x=-1 (row 0) and x=128 (row 129)
        if (tid < 48) {
            int dyi = tid / 16;
            int rem = tid % 16;
            int xi  = (rem >= 8) ? 129 : 0;
            int k8  = rem & 7;
            int4 z  = {0, 0, 0, 0};
            *(int4*)&Xs[dyi * XS_ROW + xi * XS_STRIDE + k8 * 8] = z;
        }
    }

    // ---- per-lane h-selection packs (exact fp64, identical to R1/R2) ----
    double fd = (double)(*fptr);
    unsigned hpk[2];
#pragma unroll
    for (int nt = 0; nt < 2; ++nt) {
        int x = p0 + nt * 16 + ln15;
        float d0f = depth[((size_t)b * H_N + y) * W_N + x];
        double dd = (double)d0f;
        double s0 = dd / fd;
        unsigned pk = 0;
        for (int t = 0; t < 9; ++t) {
            int dy = t / 3 - 1, dx = t % 3 - 1;
            int yy = y + dy, xx = x + dx;
            float dwf = (yy >= 0 && yy < H_N && xx >= 0 && xx < W_N)
                        ? depth[((size_t)b * H_N + yy) * W_N + xx] : 0.f;
            int h = -1;
            if (s0 > 0.0) {
                double u  = ((double)dwf - dd) / s0 + 1.5;
                double uf = floor(u);
                if (uf >= 0.0 && uf <= 2.0) h = (int)uf;
            }
            pk |= (unsigned)(h + 1) << (2 * t);
        }
        hpk[nt] = pk;
    }

    __syncthreads();

    // ---- MFMA main loop: 9 taps x (3 h x 2 kk) ----
    f32x4 acc[4][2];
#pragma unroll
    for (int mt = 0; mt < 4; ++mt)
#pragma unroll
        for (int nt = 0; nt < 2; ++nt) acc[mt][nt] = (f32x4){0.f, 0.f, 0.f, 0.f};

    const half8* wa8 = (const half8*)wa;   // frag index: (s*4 + mt)*64 + lane

    for (int t = 0; t < 9; ++t) {
        int dyi = t / 3;
        int dx  = t % 3 - 1;
        int boff0 = dyi * XS_ROW + (p0 + 0  + ln15 + dx + 1) * XS_STRIDE + quad * 8;
        int boff1 = dyi * XS_ROW + (p0 + 16 + ln15 + dx + 1) * XS_STRIDE + quad * 8;
        int hb0 = (hpk[0] >> (2 * t)) & 3;
        int hb1 = (hpk[1] >> (2 * t)) & 3;

        // batch-load all A-fragments of this tap: 6 K-steps x 4 m-tiles
        half8 A[6][4];
        {
            const half8* base = wa8 + ((size_t)t * 6 * 4) * 64 + lane;
#pragma unroll
            for (int j = 0; j < 6; ++j)
#pragma unroll
                for (int mt = 0; mt < 4; ++mt)
                    A[j][mt] = base[(j * 4 + mt) * 64];
        }

#pragma unroll
        for (int h = 0; h < 3; ++h) {
            bool m0 = (hb0 == h + 1);
            bool m1 = (hb1 == h + 1);
#pragma unroll
            for (int kk = 0; kk < 2; ++kk) {
                int j = h * 2 + kk;
                half8 b0 = *(const half8*)&Xs[boff0 + kk * 32];
                half8 b1 = *(const half8*)&Xs[boff1 + kk * 32];
                half8 z  = {(_Float16)0.f, (_Float16)0.f, (_Float16)0.f, (_Float16)0.f,
                            (_Float16)0.f, (_Float16)0.f, (_Float16)0.f, (_Float16)0.f};
                b0 = m0 ? b0 : z;
                b1 = m1 ? b1 : z;
#pragma unroll
                for (int mt = 0; mt < 4; ++mt) {
                    acc[mt][0] = __builtin_amdgcn_mfma_f32_16x16x32_f16(A[j][mt], b0, acc[mt][0], 0, 0, 0);
                    acc[mt][1] = __builtin_amdgcn_mfma_f32_16x16x32_f16(A[j][mt], b1, acc[mt][1], 0, 0, 0);
                }
            }
        }
        __syncthreads();   // lockstep the block's waves -> shared L1 A-tile
    }

    // ---- epilogue: D[m=o: quad*4+r][n=pixel: lane&15] + bias ----
#pragma unroll
    for (int mt = 0; mt < 4; ++mt) {
#pragma unroll
        for (int nt = 0; nt < 2; ++nt) {
            int x = p0 + nt * 16 + ln15;
#pragma unroll
            for (int r = 0; r < 4; ++r) {
                int o = mt * 16 + quad * 4 + r;
                out[(((size_t)b * COUT + o) * H_N + y) * W_N + x] = acc[mt][nt][r] + bias[o];
            }
        }
    }
}

// ---- fallback scalar kernel (used only if ws too small) ----
__global__ __launch_bounds__(256)
void conv25d(const float* __restrict__ inp, const float* __restrict__ depth,
             const float* __restrict__ wsrc, const float* __restrict__ bias,
             const int* __restrict__ fptr, float* __restrict__ out) {
    int bid = blockIdx.x;
    int xt  = bid & 3;
    int y   = (bid >> 2) & (H_N - 1);
    int b   = bid >> 9;
    int o   = threadIdx.x & 63;
    int q   = threadIdx.x >> 6;
    int x0  = xt * 32 + q * 8;
    double fd = (double)(*fptr);
    float acc[8];
    float bv = bias[o];
#pragma unroll
    for (int i = 0; i < 8; ++i) acc[i] = bv;
    const float* dcen = depth + ((size_t)b * H_N + y) * W_N;
    float d0[8];
#pragma unroll
    for (int i = 0; i < 8; ++i) d0[i] = dcen[x0 + i];
    for (int t = 0; t < 9; ++t) {
        int dy = t / 3 - 1, dx = t % 3 - 1;
        int yy = y + dy;
        if (yy < 0 || yy >= H_N) continue;
        const float* drow = depth + ((size_t)b * H_N + yy) * W_N;
        int hsel[8];
#pragma unroll
        for (int i = 0; i < 8; ++i) {
            int xx = x0 + i + dx;
            int h = -1;
            if (xx >= 0 && xx < W_N) {
                double dd = (double)d0[i];
                double s0 = dd / fd;
                if (s0 > 0.0) {
                    double u = ((double)drow[xx] - dd) / s0 + 1.5;
                    double uf = floor(u);
                    if (uf >= 0.0 && uf <= 2.0) h = (int)uf;
                }
            }
            hsel[i] = h;
        }
        const float* irow = inp + ((size_t)b * CIN * H_N + yy) * W_N;
        for (int c = 0; c < CIN; ++c) {
            const float* wb = wsrc + ((size_t)o * CIN + c) * 9 + t;
            float w0 = wb[0], w1 = wb[(size_t)COUT * CIN * 9], w2 = wb[2 * (size_t)COUT * CIN * 9];
            const float* ir = irow + (size_t)c * H_N * W_N;
#pragma unroll
            for (int i = 0; i < 8; ++i) {
                int h = hsel[i];
                if (h >= 0) {
                    float wv = (h == 0) ? w0 : ((h == 1) ? w1 : w2);
                    acc[i] = fmaf(ir[x0 + i + dx], wv, acc[i]);
                }
            }
        }
    }
    float* orow = out + (((size_t)b * COUT + o) * H_N + y) * W_N;
#pragma unroll
    for (int i = 0; i < 8; ++i) orow[x0 + i] = acc[i];
}

extern "C" void kernel_launch(void* const* d_in, const int* in_sizes, int n_in,
                              void* d_out, int out_size, void* d_ws, size_t ws_size,
                              hipStream_t stream) {
    const float* inp   = (const float*)d_in[0];
    const float* depth = (const float*)d_in[1];
    const float* w     = (const float*)d_in[2];
    const float* bias  = (const float*)d_in[3];
    const int*   f     = (const int*)d_in[4];
    float* out = (float*)d_out;

    if (ws_size >= WA_BYTES) {
        _Float16* wa = (_Float16*)d_ws;
        wprep<<<NSTEP, 256, 0, stream>>>(w, wa);
        conv_mfma<<<B_N * H_N, 256, 0, stream>>>(inp, depth, wa, bias, f, out);
    } else {
        conv25d<<<B_N * H_N * (W_N / 32), 256, 0, stream>>>(inp, depth, w, bias, f, out);
    }
}